// Round 12
// baseline (1816.405 us; speedup 1.0000x reference)
//
#include <hip/hip_runtime.h>
#include <hip/hip_bf16.h>

// ---------------------------------------------------------------------------
// MoE top-2 FFN, MI355X round 12 (= round 10 design, resubmit; infra:
// 5x acquisition timeout + 1x container-failed). Presplit-x bf16 planes
// (ws-gated) + T14 global->reg prefetch.
// T=8192, D=1024, H=4096, E=8, top_k=2, erf GELU.
//
// vs round 9 (1532us; ffn1 615us, MfmaUtil 31 / VALUBusy 34 / ~35% waits):
//   - split_x kernel: x -> x_hi/x_lo bf16 planes once (ffn1 A-stage = copy,
//     kills ~2/3 of staging VALU). Only if ws_size >= 161MB, else fallback
//     to round-9 ffn1 (in-kernel split).
//   - T14 prefetch in ffn1/ffn2: next K-step's global loads issue before the
//     barrier, latency hides under MFMA phase (loads land in regs, LDS-write
//     next iteration).
// ws layout: [1MB meta][128MB Hbuf][16MB x_hi][16MB x_lo] = 161MB (gated).
// If next round fails with a container error again: bisect by resubmitting
// round-9 known-good source.
// ---------------------------------------------------------------------------

#define T_TOK 8192
#define DDIM  1024
#define HDIM  4096
#define NEXP  8

typedef __attribute__((ext_vector_type(8))) short sv8;   // 8 bf16 = 4 VGPR
typedef __attribute__((ext_vector_type(4))) float fv4;   // MFMA acc

__device__ __forceinline__ float gelu_erf(float v) {
    return 0.5f * v * (1.0f + erff(v * 0.70710678118654752f));
}

__device__ __forceinline__ short cvt_bf16(float f) {   // RNE via HW cvt
    __hip_bfloat16 b = __float2bfloat16(f);
    unsigned short s; __builtin_memcpy(&s, &b, 2);
    return (short)s;
}

// split f into hi (bf16 RNE) + lo (bf16 of exact residual)
__device__ __forceinline__ void split2(float f, short& h, short& l) {
    h = cvt_bf16(f);
    unsigned int hb = ((unsigned int)(unsigned short)h) << 16;
    float hf; __builtin_memcpy(&hf, &hb, 4);
    l = cvt_bf16(f - hf);
}

// ---------------------------------------------------------------------------
__global__ __launch_bounds__(256) void zero_kernel(float* __restrict__ out,
                                                   int n, int* __restrict__ counts) {
    int i = blockIdx.x * 256 + threadIdx.x;
    if (i < n) out[i] = 0.0f;
    if (blockIdx.x == 0 && threadIdx.x < 16) counts[threadIdx.x] = 0;
}

// x [T][D] fp32 -> x_hi/x_lo bf16 planes (same rounding as in-kernel split2)
__global__ __launch_bounds__(256) void split_x_kernel(
    const float* __restrict__ x, unsigned short* __restrict__ xh,
    unsigned short* __restrict__ xl) {
    const size_t i = ((size_t)blockIdx.x * 256 + threadIdx.x) * 8;
    if (i >= (size_t)T_TOK * DDIM) return;
    const float4 f0 = *(const float4*)(x + i);
    const float4 f1 = *(const float4*)(x + i + 4);
    const float f[8] = {f0.x, f0.y, f0.z, f0.w, f1.x, f1.y, f1.z, f1.w};
    sv8 hv, lv;
#pragma unroll
    for (int j = 0; j < 8; ++j) { short hh, ll; split2(f[j], hh, ll); hv[j] = hh; lv[j] = ll; }
    *(sv8*)(xh + i) = hv;
    *(sv8*)(xl + i) = lv;
}

__global__ __launch_bounds__(256) void gate_kernel(
    const float* __restrict__ x, const float* __restrict__ gw,
    const float* __restrict__ gb, int* __restrict__ counts,
    int* __restrict__ tok_idx, float* __restrict__ tok_gate) {
    const int token = blockIdx.x * 4 + (threadIdx.x >> 6);
    const int lane  = threadIdx.x & 63;
    const float* xr = x + (size_t)token * DDIM;

    float acc[8] = {0.f, 0.f, 0.f, 0.f, 0.f, 0.f, 0.f, 0.f};
    for (int d = lane; d < DDIM; d += 64) {
        const float xv = xr[d];
        const float4 g0 = *(const float4*)(gw + d * NEXP);
        const float4 g1 = *(const float4*)(gw + d * NEXP + 4);
        acc[0] = fmaf(xv, g0.x, acc[0]); acc[1] = fmaf(xv, g0.y, acc[1]);
        acc[2] = fmaf(xv, g0.z, acc[2]); acc[3] = fmaf(xv, g0.w, acc[3]);
        acc[4] = fmaf(xv, g1.x, acc[4]); acc[5] = fmaf(xv, g1.y, acc[5]);
        acc[6] = fmaf(xv, g1.z, acc[6]); acc[7] = fmaf(xv, g1.w, acc[7]);
    }
#pragma unroll
    for (int e = 0; e < 8; ++e)
        for (int off = 32; off > 0; off >>= 1)
            acc[e] += __shfl_down(acc[e], off);

    if (lane == 0) {
#pragma unroll
        for (int e = 0; e < 8; ++e) acc[e] += gb[e];
        float m = acc[0];
#pragma unroll
        for (int e = 1; e < 8; ++e) m = fmaxf(m, acc[e]);
        float p[8], s = 0.f;
#pragma unroll
        for (int e = 0; e < 8; ++e) { p[e] = expf(acc[e] - m); s += p[e]; }
        const float inv = 1.0f / s;
#pragma unroll
        for (int e = 0; e < 8; ++e) p[e] *= inv;
        int i1 = 0;
#pragma unroll
        for (int e = 1; e < 8; ++e) if (p[e] > p[i1]) i1 = e;
        int i2 = (i1 == 0) ? 1 : 0;
#pragma unroll
        for (int e = 0; e < 8; ++e) if (e != i1 && p[e] > p[i2]) i2 = e;

        int pos1 = atomicAdd(&counts[i1], 1);
        tok_idx[i1 * T_TOK + pos1]  = token;
        tok_gate[i1 * T_TOK + pos1] = p[i1];
        int pos2 = atomicAdd(&counts[i2], 1);
        tok_idx[i2 * T_TOK + pos2]  = token;
        tok_gate[i2 * T_TOK + pos2] = p[i2];
    }
}

__global__ void offs_kernel(const int* __restrict__ counts, int* __restrict__ offs) {
    if (threadIdx.x == 0 && blockIdx.x == 0) {
        int s = 0;
#pragma unroll
        for (int e = 0; e < NEXP; ++e) { offs[e] = s; s += counts[e]; }
        offs[NEXP] = s;
    }
}

// ---------------------------------------------------------------------------
// FFN1 presplit path: A = x_hi/x_lo copy, B = w1 split on the fly,
// T14 prefetch of next K-step into regs. 256x128, 512 thr, BK=32.
__global__ __launch_bounds__(512) void ffn1_ps2(
    const unsigned short* __restrict__ xh, const unsigned short* __restrict__ xl,
    const float* __restrict__ w1, const float* __restrict__ b1,
    const int* __restrict__ counts, const int* __restrict__ offs,
    const int* __restrict__ tok_idx, unsigned short* __restrict__ Hbuf) {
    const int e   = blockIdx.z;
    const int cnt = counts[e];
    const int m0  = blockIdx.y * 256;
    if (m0 >= cnt) return;
    const int n0  = blockIdx.x * 128;

    __shared__ __align__(16) short Ah[256][40], Al[256][40];
    __shared__ __align__(16) short Bh[128][40], Bl[128][40];
    __shared__ int stok[256];

    const int tid  = threadIdx.x;
    const int lane = tid & 63;
    const int wv   = tid >> 6;
    const int wr   = wv >> 1, wc = wv & 1;
    const int r16  = lane & 15, g4 = lane >> 4;

    if (tid < 256) stok[tid] = tok_idx[e * T_TOK + min(m0 + tid, cnt - 1)];
    __syncthreads();

    const float* W = w1 + (size_t)e * DDIM * HDIM;

    const int ar0 = tid >> 2, ar1 = 128 + (tid >> 2), akc = tid & 3;
    const size_t t0 = (size_t)stok[ar0] * DDIM + akc * 8;
    const size_t t1 = (size_t)stok[ar1] * DDIM + akc * 8;
    const int bn = tid >> 2, bkc = tid & 3;

    // prologue prefetch (k0 = 0)
    sv8 pah0 = *(const sv8*)(xh + t0);
    sv8 pal0 = *(const sv8*)(xl + t0);
    sv8 pah1 = *(const sv8*)(xh + t1);
    sv8 pal1 = *(const sv8*)(xl + t1);
    float pb[8];
#pragma unroll
    for (int i = 0; i < 8; ++i) pb[i] = W[(size_t)(bkc * 8 + i) * HDIM + n0 + bn];

    fv4 acc[4][4];
    const fv4 z4 = {0.f, 0.f, 0.f, 0.f};
#pragma unroll
    for (int i = 0; i < 4; ++i)
#pragma unroll
        for (int j = 0; j < 4; ++j) acc[i][j] = z4;

    for (int k0 = 0; k0 < DDIM; k0 += 32) {
        // ---- LDS write from prefetch regs ----
        *(sv8*)&Ah[ar0][akc * 8] = pah0;
        *(sv8*)&Al[ar0][akc * 8] = pal0;
        *(sv8*)&Ah[ar1][akc * 8] = pah1;
        *(sv8*)&Al[ar1][akc * 8] = pal1;
        {
            sv8 hv, lv;
#pragma unroll
            for (int i = 0; i < 8; ++i) { short hh, ll; split2(pb[i], hh, ll); hv[i] = hh; lv[i] = ll; }
            *(sv8*)&Bh[bn][bkc * 8] = hv;
            *(sv8*)&Bl[bn][bkc * 8] = lv;
        }
        // ---- issue next K-step's global loads (latency hides under MFMA) ----
        const int k1 = k0 + 32;
        if (k1 < DDIM) {
            pah0 = *(const sv8*)(xh + t0 + k1);
            pal0 = *(const sv8*)(xl + t0 + k1);
            pah1 = *(const sv8*)(xh + t1 + k1);
            pal1 = *(const sv8*)(xl + t1 + k1);
#pragma unroll
            for (int i = 0; i < 8; ++i)
                pb[i] = W[(size_t)(k1 + bkc * 8 + i) * HDIM + n0 + bn];
        }
        __syncthreads();

        // ---- fragments + MFMA (3-term split: hh + hl + lh) ----
        sv8 a_h[4], a_l[4], b_h[4], b_l[4];
#pragma unroll
        for (int m = 0; m < 4; ++m) {
            const int row = wr * 64 + m * 16 + r16;
            a_h[m] = *(const sv8*)&Ah[row][g4 * 8];
            a_l[m] = *(const sv8*)&Al[row][g4 * 8];
        }
#pragma unroll
        for (int n = 0; n < 4; ++n) {
            const int col = wc * 64 + n * 16 + r16;
            b_h[n] = *(const sv8*)&Bh[col][g4 * 8];
            b_l[n] = *(const sv8*)&Bl[col][g4 * 8];
        }
#pragma unroll
        for (int m = 0; m < 4; ++m)
#pragma unroll
            for (int n = 0; n < 4; ++n) {
                acc[m][n] = __builtin_amdgcn_mfma_f32_16x16x32_bf16(a_h[m], b_h[n], acc[m][n], 0, 0, 0);
                acc[m][n] = __builtin_amdgcn_mfma_f32_16x16x32_bf16(a_h[m], b_l[n], acc[m][n], 0, 0, 0);
                acc[m][n] = __builtin_amdgcn_mfma_f32_16x16x32_bf16(a_l[m], b_h[n], acc[m][n], 0, 0, 0);
            }
        __syncthreads();
    }

    const int hbase = offs[e] + m0;
#pragma unroll
    for (int n = 0; n < 4; ++n) {
        const int colg = n0 + wc * 64 + n * 16 + r16;
        const float bias = b1[e * HDIM + colg];
#pragma unroll
        for (int m = 0; m < 4; ++m) {
#pragma unroll
            for (int r = 0; r < 4; ++r) {
                const int rowl = wr * 64 + m * 16 + g4 * 4 + r;
                if (m0 + rowl < cnt) {
                    const float v = gelu_erf(acc[m][n][r] + bias);
                    Hbuf[(size_t)(hbase + rowl) * HDIM + colg] = (unsigned short)cvt_bf16(v);
                }
            }
        }
    }
}

// ---------------------------------------------------------------------------
// FFN1 fallback (= round 9 measured 615us, known-correct; used if ws < 161MB)
__global__ __launch_bounds__(512) void ffn1_fb(
    const float* __restrict__ x, const float* __restrict__ w1,
    const float* __restrict__ b1, const int* __restrict__ counts,
    const int* __restrict__ offs, const int* __restrict__ tok_idx,
    unsigned short* __restrict__ Hbuf) {
    const int e   = blockIdx.z;
    const int cnt = counts[e];
    const int m0  = blockIdx.y * 256;
    if (m0 >= cnt) return;
    const int n0  = blockIdx.x * 128;

    __shared__ __align__(16) short Ah[256][40], Al[256][40];
    __shared__ __align__(16) short Bh[128][40], Bl[128][40];
    __shared__ int stok[256];

    const int tid  = threadIdx.x;
    const int lane = tid & 63;
    const int wv   = tid >> 6;
    const int wr   = wv >> 1, wc = wv & 1;
    const int r16  = lane & 15, g4 = lane >> 4;

    if (tid < 256) stok[tid] = tok_idx[e * T_TOK + min(m0 + tid, cnt - 1)];
    __syncthreads();

    const float* W = w1 + (size_t)e * DDIM * HDIM;

    fv4 acc[4][4];
    const fv4 z4 = {0.f, 0.f, 0.f, 0.f};
#pragma unroll
    for (int i = 0; i < 4; ++i)
#pragma unroll
        for (int j = 0; j < 4; ++j) acc[i][j] = z4;

    for (int k0 = 0; k0 < DDIM; k0 += 32) {
#pragma unroll
        for (int h = 0; h < 2; ++h) {
            const int c   = tid + h * 512;
            const int row = c >> 2, kc = c & 3;
            const float* src = x + (size_t)stok[row] * DDIM + k0 + kc * 8;
            const float4 f0 = *(const float4*)src;
            const float4 f1 = *(const float4*)(src + 4);
            const float f[8] = {f0.x, f0.y, f0.z, f0.w, f1.x, f1.y, f1.z, f1.w};
            sv8 hv, lv;
#pragma unroll
            for (int i = 0; i < 8; ++i) { short hh, ll; split2(f[i], hh, ll); hv[i] = hh; lv[i] = ll; }
            *(sv8*)&Ah[row][kc * 8] = hv;
            *(sv8*)&Al[row][kc * 8] = lv;
        }
        {
            const int nn = tid >> 2, kc = tid & 3;
            float f[8];
#pragma unroll
            for (int i = 0; i < 8; ++i)
                f[i] = W[(size_t)(k0 + kc * 8 + i) * HDIM + n0 + nn];
            sv8 hv, lv;
#pragma unroll
            for (int i = 0; i < 8; ++i) { short hh, ll; split2(f[i], hh, ll); hv[i] = hh; lv[i] = ll; }
            *(sv8*)&Bh[nn][kc * 8] = hv;
            *(sv8*)&Bl[nn][kc * 8] = lv;
        }
        __syncthreads();

        sv8 a_h[4], a_l[4], b_h[4], b_l[4];
#pragma unroll
        for (int m = 0; m < 4; ++m) {
            const int row = wr * 64 + m * 16 + r16;
            a_h[m] = *(const sv8*)&Ah[row][g4 * 8];
            a_l[m] = *(const sv8*)&Al[row][g4 * 8];
        }
#pragma unroll
        for (int n = 0; n < 4; ++n) {
            const int col = wc * 64 + n * 16 + r16;
            b_h[n] = *(const sv8*)&Bh[col][g4 * 8];
            b_l[n] = *(const sv8*)&Bl[col][g4 * 8];
        }
#pragma unroll
        for (int m = 0; m < 4; ++m)
#pragma unroll
            for (int n = 0; n < 4; ++n) {
                acc[m][n] = __builtin_amdgcn_mfma_f32_16x16x32_bf16(a_h[m], b_h[n], acc[m][n], 0, 0, 0);
                acc[m][n] = __builtin_amdgcn_mfma_f32_16x16x32_bf16(a_h[m], b_l[n], acc[m][n], 0, 0, 0);
                acc[m][n] = __builtin_amdgcn_mfma_f32_16x16x32_bf16(a_l[m], b_h[n], acc[m][n], 0, 0, 0);
            }
        __syncthreads();
    }

    const int hbase = offs[e] + m0;
#pragma unroll
    for (int n = 0; n < 4; ++n) {
        const int colg = n0 + wc * 64 + n * 16 + r16;
        const float bias = b1[e * HDIM + colg];
#pragma unroll
        for (int m = 0; m < 4; ++m) {
#pragma unroll
            for (int r = 0; r < 4; ++r) {
                const int rowl = wr * 64 + m * 16 + g4 * 4 + r;
                if (m0 + rowl < cnt) {
                    const float v = gelu_erf(acc[m][n][r] + bias);
                    Hbuf[(size_t)(hbase + rowl) * HDIM + colg] = (unsigned short)cvt_bf16(v);
                }
            }
        }
    }
}

// ---------------------------------------------------------------------------
// FFN2: A = Hbuf bf16 copy, B = w2 split, 2-term MFMA; T14 prefetch.
__global__ __launch_bounds__(512) void ffn2_mfma(
    const unsigned short* __restrict__ Hb, const float* __restrict__ w2,
    const float* __restrict__ b2, const int* __restrict__ counts,
    const int* __restrict__ offs, const int* __restrict__ tok_idx,
    const float* __restrict__ tok_gate, float* __restrict__ out) {
    const int e   = blockIdx.z;
    const int cnt = counts[e];
    const int m0  = blockIdx.y * 256;
    if (m0 >= cnt) return;
    const int n0  = blockIdx.x * 128;

    __shared__ __align__(16) short Ahs[256][40];
    __shared__ __align__(16) short Bh[128][40], Bl[128][40];
    __shared__ int   stok[256];
    __shared__ float sgate[256];

    const int tid  = threadIdx.x;
    const int lane = tid & 63;
    const int wv   = tid >> 6;
    const int wr   = wv >> 1, wc = wv & 1;
    const int r16  = lane & 15, g4 = lane >> 4;

    if (tid < 256) {
        const int src = e * T_TOK + min(m0 + tid, cnt - 1);
        stok[tid]  = tok_idx[src];
        sgate[tid] = tok_gate[src];
    }
    __syncthreads();

    const float* W = w2 + (size_t)e * HDIM * DDIM;
    const int oe = offs[e];

    const int ar0 = tid >> 2, ar1 = 128 + (tid >> 2), akc = tid & 3;
    const size_t g0r = (size_t)(oe + min(m0 + ar0, cnt - 1)) * HDIM + akc * 8;
    const size_t g1r = (size_t)(oe + min(m0 + ar1, cnt - 1)) * HDIM + akc * 8;
    const int bn = tid >> 2, bkc = tid & 3;

    // prologue prefetch (k0 = 0)
    sv8 pa0 = *(const sv8*)(Hb + g0r);
    sv8 pa1 = *(const sv8*)(Hb + g1r);
    float pb[8];
#pragma unroll
    for (int i = 0; i < 8; ++i) pb[i] = W[(size_t)(bkc * 8 + i) * DDIM + n0 + bn];

    fv4 acc[4][4];
    const fv4 z4 = {0.f, 0.f, 0.f, 0.f};
#pragma unroll
    for (int i = 0; i < 4; ++i)
#pragma unroll
        for (int j = 0; j < 4; ++j) acc[i][j] = z4;

    for (int k0 = 0; k0 < HDIM; k0 += 32) {
        // ---- LDS write from prefetch regs ----
        *(sv8*)&Ahs[ar0][akc * 8] = pa0;
        *(sv8*)&Ahs[ar1][akc * 8] = pa1;
        {
            sv8 hv, lv;
#pragma unroll
            for (int i = 0; i < 8; ++i) { short hh, ll; split2(pb[i], hh, ll); hv[i] = hh; lv[i] = ll; }
            *(sv8*)&Bh[bn][bkc * 8] = hv;
            *(sv8*)&Bl[bn][bkc * 8] = lv;
        }
        // ---- issue next K-step's global loads ----
        const int k1 = k0 + 32;
        if (k1 < HDIM) {
            pa0 = *(const sv8*)(Hb + g0r + k1);
            pa1 = *(const sv8*)(Hb + g1r + k1);
#pragma unroll
            for (int i = 0; i < 8; ++i)
                pb[i] = W[(size_t)(k1 + bkc * 8 + i) * DDIM + n0 + bn];
        }
        __syncthreads();

        sv8 a[4], b_h[4], b_l[4];
#pragma unroll
        for (int m = 0; m < 4; ++m) {
            const int row = wr * 64 + m * 16 + r16;
            a[m] = *(const sv8*)&Ahs[row][g4 * 8];
        }
#pragma unroll
        for (int n = 0; n < 4; ++n) {
            const int col = wc * 64 + n * 16 + r16;
            b_h[n] = *(const sv8*)&Bh[col][g4 * 8];
            b_l[n] = *(const sv8*)&Bl[col][g4 * 8];
        }
#pragma unroll
        for (int m = 0; m < 4; ++m)
#pragma unroll
            for (int n = 0; n < 4; ++n) {
                acc[m][n] = __builtin_amdgcn_mfma_f32_16x16x32_bf16(a[m], b_h[n], acc[m][n], 0, 0, 0);
                acc[m][n] = __builtin_amdgcn_mfma_f32_16x16x32_bf16(a[m], b_l[n], acc[m][n], 0, 0, 0);
            }
        __syncthreads();
    }

#pragma unroll
    for (int n = 0; n < 4; ++n) {
        const int colg = n0 + wc * 64 + n * 16 + r16;
        const float bias = b2[e * DDIM + colg];
#pragma unroll
        for (int m = 0; m < 4; ++m) {
#pragma unroll
            for (int r = 0; r < 4; ++r) {
                const int rowl = wr * 64 + m * 16 + g4 * 4 + r;
                if (m0 + rowl < cnt) {
                    const int   t  = stok[rowl];
                    const float gg = sgate[rowl];
                    atomicAdd(&out[(size_t)t * DDIM + colg], gg * (acc[m][n][r] + bias));
                }
            }
        }
    }
}

// ---------------------------------------------------------------------------
extern "C" void kernel_launch(void* const* d_in, const int* in_sizes, int n_in,
                              void* d_out, int out_size, void* d_ws, size_t ws_size,
                              hipStream_t stream) {
    const float* x      = (const float*)d_in[0];
    const float* gate_w = (const float*)d_in[1];
    const float* gate_b = (const float*)d_in[2];
    const float* w1     = (const float*)d_in[3];
    const float* b1     = (const float*)d_in[4];
    const float* w2     = (const float*)d_in[5];
    const float* b2     = (const float*)d_in[6];

    char* ws        = (char*)d_ws;
    int*   counts   = (int*)ws;
    int*   offs     = (int*)(ws + 64);
    int*   tok_idx  = (int*)(ws + 1024);
    float* tok_gate = (float*)(ws + 1024 + 262144);
    unsigned short* Hbuf = (unsigned short*)(ws + (1 << 20));           // 128MB
    const size_t hb_bytes = (size_t)2 * T_TOK * HDIM * sizeof(unsigned short);
    unsigned short* xhi = (unsigned short*)(ws + (1 << 20) + hb_bytes); // 16MB
    unsigned short* xlo = xhi + (size_t)T_TOK * DDIM;                   // 16MB

    const size_t need_ps = (size_t)(1 << 20) + hb_bytes
                         + (size_t)2 * T_TOK * DDIM * sizeof(unsigned short);
    const bool presplit = ws_size >= need_ps;   // host-constant -> graph-stable

    float* out = (float*)d_out;

    zero_kernel<<<(T_TOK * DDIM + 255) / 256, 256, 0, stream>>>(out, T_TOK * DDIM, counts);
    gate_kernel<<<T_TOK / 4, 256, 0, stream>>>(x, gate_w, gate_b, counts, tok_idx, tok_gate);
    offs_kernel<<<1, 64, 0, stream>>>(counts, offs);

    dim3 g1(HDIM / 128, T_TOK / 256, NEXP);
    dim3 g2(DDIM / 128, T_TOK / 256, NEXP);
    if (presplit) {
        split_x_kernel<<<(T_TOK * DDIM) / (256 * 8), 256, 0, stream>>>(x, xhi, xlo);
        ffn1_ps2<<<g1, 512, 0, stream>>>(xhi, xlo, w1, b1, counts, offs, tok_idx, Hbuf);
    } else {
        ffn1_fb<<<g1, 512, 0, stream>>>(x, w1, b1, counts, offs, tok_idx, Hbuf);
    }
    ffn2_mfma<<<g2, 512, 0, stream>>>(Hbuf, w2, b2, counts, offs, tok_idx, tok_gate, out);
}